// Round 1
// 266.873 us; speedup vs baseline: 1.0139x; 1.0139x over previous
//
#include <hip/hip_runtime.h>
#include <math.h>

// Problem constants (x: [4, 64, 384, 384] fp32)
#define QLS_T   256            // B*C = 4*64, sequential scan axis
#define QLS_HW  (384 * 384)    // independent spatial locations

// Quantizer constants from the reference
#define Q_SCALE      16.0f
#define INV_Q_SCALE  (1.0f / 16.0f)
#define QMAXF        7.9375f
#define QMINF        (-8.0f)
#define LUT_IN_SCALE 4096.0f
#define LUT_IN_MAX   32767.0f
#define INV_LUT_OUT  (1.0f / 65536.0f)

// log1p(exp(-d)) = log2(1 + 2^(-d*log2e)) * ln2, on raw v_exp_f32/v_log_f32.
#define NEG_LOG2E_DIV (-1.4426950408889634f / 4096.0f)
#define LN2_X_65536   45426.09375f

// Software-prefetch depth for the scan pass. 16 in-flight dword loads/wave
// x 9 waves/CU x 256B/wave-load = 36KB/CU in flight >> 9KB needed to cover
// ~900cy HBM latency at 10B/cyc/CU. R2 theory: VGPR_Count=12 showed the
// compiler kept only ~2 loads in flight -> scan ran one HBM latency per
// step (256 x ~900cy ~= 96us). Explicit statically-indexed register
// double-buffer forces the MLP.
#define PF 16

__device__ __forceinline__ float qls_step(float s, float v) {
    float diff = fabsf(s - v);
    // d_int = min(floor(diff*4096), 32767); exact LUT grid
    float d_int = fminf(floorf(diff * LUT_IN_SCALE), LUT_IN_MAX);
    // lu = round(log1p(exp(-d_q))*65536)/65536 via v_exp_f32 + v_log_f32
    float e  = __builtin_amdgcn_exp2f(d_int * NEG_LOG2E_DIV);
    float lu = rintf(__builtin_amdgcn_logf(1.0f + e) * LN2_X_65536) * INV_LUT_OUT;
    s = fmaxf(s, v) + lu;                         // max(sum_exp, t) + lu
    return fminf(fmaxf(s, QMINF), QMAXF);         // clip(s, QMIN, QMAX)
}

// One thread per spatial location. 147456 threads = 2304 blocks x 64
// = exactly 9 waves/CU on 256 CUs (single-wave blocks, perfect balance).
__global__ __launch_bounds__(64) void QuantizedLogSoftmax_12970801234623_kernel(
    const float* __restrict__ x, float* __restrict__ out) {
    const int i = blockIdx.x * 64 + threadIdx.x;   // spatial index in [0, HW)
    const float* xp = x + i;

    // Prologue: preload first PF scan inputs.
    float buf[PF];
    #pragma unroll
    for (int p = 0; p < PF; ++p) buf[p] = xp[p * QLS_HW];

    float s = QMINF;
    // Steady state: issue the next PF loads, then run PF serial scan steps
    // (~960cy of dependent VALU) underneath them, then rotate the buffer.
    // All array indices are compile-time constant after unroll -> registers,
    // no scratch.
    for (int t0 = 0; t0 < QLS_T - PF; t0 += PF) {
        float nxt[PF];
        #pragma unroll
        for (int p = 0; p < PF; ++p) nxt[p] = xp[(t0 + PF + p) * QLS_HW];
        #pragma unroll
        for (int p = 0; p < PF; ++p) s = qls_step(s, buf[p]);
        #pragma unroll
        for (int p = 0; p < PF; ++p) buf[p] = nxt[p];
    }
    // Epilogue group (no prefetch left).
    #pragma unroll
    for (int p = 0; p < PF; ++p) s = qls_step(s, buf[p]);

    // Output pass: re-read x (L3-resident; FETCH_SIZE confirms single HBM
    // read), quantize to the 1/16 grid. Iterations are fully independent, so
    // a wide unroll gives the scheduler 16 L3-latency loads to overlap.
    // Non-temporal stores: out is never re-read.
    float* op = out + i;
    #pragma unroll 16
    for (int t = 0; t < QLS_T; ++t) {
        float v = xp[t * QLS_HW];
        float q = fminf(fmaxf(rintf((v - s) * Q_SCALE), -128.0f), 127.0f);
        __builtin_nontemporal_store(q * INV_Q_SCALE, op + t * QLS_HW);
    }
}

extern "C" void kernel_launch(void* const* d_in, const int* in_sizes, int n_in,
                              void* d_out, int out_size, void* d_ws, size_t ws_size,
                              hipStream_t stream) {
    const float* x = (const float*)d_in[0];
    float* out = (float*)d_out;
    const int threads = 64;
    const int blocks = QLS_HW / threads;  // 2304
    QuantizedLogSoftmax_12970801234623_kernel<<<blocks, threads, 0, stream>>>(x, out);
}